// Round 8
// baseline (474.086 us; speedup 1.0000x reference)
//
#include <hip/hip_runtime.h>
#include <hip/hip_cooperative_groups.h>
#include <math.h>

namespace cg = cooperative_groups;

// e0 = 4*((1/3)^12 - (1/3)^6); 0.5*pe = 2*(c12 - c6) - 0.5*e0
static constexpr float HALF_NEG_E0 = 2.739720872e-3f; // -0.5*e0

#define T 256           // threads per block
#define B1 2500         // blocks for legacy p3
#define SHIFT 10
#define BK 1024         // nodes per bucket (lid fits in 10 bits)
#define QS 3            // log2 sub-blocks per bucket in p4a (S2=8, proven)
#define GPB 640         // groups per chunk per block (proven p3 geometry)
#define CAPB 2560       // staged entries per chunk = GPB*4
#define MAXBLK 1024     // cooperative grid cap
#define FPSCALE 512.0f  // |f| <= 59.5 -> |int| <= 30450 < 32767
#define INV_FPSCALE (1.0f / 512.0f)

// smem ints: s_ent(2*CAPB) + s_bkt(CAPB/4) + lcur(128) + gml(128) + wsum(4)
#define SMEM_INTS (2 * CAPB + CAPB / 4 + 128 + 128 + 4)
#define SMEM_BYTES (SMEM_INTS * 4)

// ======================= single cooperative kernel ==========================
// phase0: zero gcur | gsync | phase3 xN chunks (hist->scan->reserve->compute->
// flush, identical to proven 86us kernel) + eblk store | gsync | phase4a
// partial reduce (packed u64 LDS atomics) | gsync | phase4b merge + energy.
__global__ __launch_bounds__(T)
void lj_coop(const float* __restrict__ bv, const int* __restrict__ dst,
             unsigned* __restrict__ gcur, int2* __restrict__ sorted,
             float* __restrict__ eblk,
             unsigned long long* __restrict__ partXY, int* __restrict__ partZ,
             float* __restrict__ forces, float* __restrict__ analytic,
             float* __restrict__ energy,
             int E, int N, int NB, int cap, int nchunks)
{
    cg::grid_group grid = cg::this_grid();
    extern __shared__ int smem[];
    int2*          s_ent = (int2*)smem;                      // [CAPB]
    unsigned char* s_bkt = (unsigned char*)(smem + 2 * CAPB);// [CAPB]
    int* lcur = smem + 2 * CAPB + CAPB / 4;                  // [128]
    int* gml  = lcur + 128;                                  // [128]
    float* wsum = (float*)(gml + 128);                       // [4]

    const int t = threadIdx.x;
    const int G = (E + 3) >> 2;

    // ---- phase 0: zero the bucket cursors ----------------------------------
    {
        const int idx = blockIdx.x * T + t;
        if (idx < NB) gcur[idx] = 0u;
    }
    grid.sync();

    const int4*   __restrict__ d4  = (const int4*)dst;
    const float4* __restrict__ bv4 = (const float4*)bv;
    float esum = 0.0f;

    // ---- phase 3: chunked (proven 640-group geometry per chunk) ------------
    for (int c = 0; c < nchunks; ++c) {
        const int gs = (c * (int)gridDim.x + (int)blockIdx.x) * GPB;
        const int ge = min(G, gs + GPB);

        __syncthreads();                      // prev flush done before reuse
        for (int b = t; b < NB; b += T) lcur[b] = 0;
        __syncthreads();

        // pass A: local bucket histogram
        for (int g = gs + t; g < ge; g += T) {
            const int e0 = g << 2;
            if (e0 + 3 < E) {
                int4 d = d4[g];
                atomicAdd(&lcur[((unsigned)d.x) >> SHIFT], 1);
                atomicAdd(&lcur[((unsigned)d.y) >> SHIFT], 1);
                atomicAdd(&lcur[((unsigned)d.z) >> SHIFT], 1);
                atomicAdd(&lcur[((unsigned)d.w) >> SHIFT], 1);
            } else {
                for (int e = e0; e < E; ++e)
                    atomicAdd(&lcur[((unsigned)dst[e]) >> SHIFT], 1);
            }
        }
        __syncthreads();

        // 128-wide exclusive scan (NB <= 128)
        int* sc = (int*)s_ent;
        if (t < 128) sc[t] = (t < NB) ? lcur[t] : 0;
        __syncthreads();
#pragma unroll
        for (int off = 1; off < 128; off <<= 1) {
            int a0 = (t < 128 && t >= off) ? sc[t - off] : 0;
            __syncthreads();
            if (t < 128) sc[t] += a0;
            __syncthreads();
        }
        // reserve region slices (one global atomic per bucket)
        if (t < NB) {
            int cnt = lcur[t];
            int ex  = sc[t] - cnt;
            unsigned ret = atomicAdd(&gcur[t], (unsigned)cnt);
            gml[t]  = t * cap + (int)ret - ex;
            lcur[t] = ex;
        }
        __syncthreads();

        // pass B: compute + LDS bucket-grouped staging
        for (int g = gs + t; g < ge; g += T) {
            const int e0 = g << 2;
            float ex4[4], ey[4], ez[4]; int dd[4];
            int nk;
            if (e0 + 3 < E) {
                float4 a  = bv4[3 * g + 0];
                float4 b2 = bv4[3 * g + 1];
                float4 cc = bv4[3 * g + 2];
                int4 d = d4[g];
                ex4[0] = a.x;  ey[0] = a.y;  ez[0] = a.z;
                ex4[1] = a.w;  ey[1] = b2.x; ez[1] = b2.y;
                ex4[2] = b2.z; ey[2] = b2.w; ez[2] = cc.x;
                ex4[3] = cc.y; ey[3] = cc.z; ez[3] = cc.w;
                dd[0] = d.x; dd[1] = d.y; dd[2] = d.z; dd[3] = d.w;
                nk = 4;
            } else {
                nk = E - e0;
                for (int k = 0; k < nk; ++k) {
                    ex4[k] = bv[3 * (e0 + k) + 0];
                    ey[k]  = bv[3 * (e0 + k) + 1];
                    ez[k]  = bv[3 * (e0 + k) + 2];
                    dd[k]  = dst[e0 + k];
                }
            }
            for (int k = 0; k < nk; ++k) {
                float x = ex4[k], y = ey[k], z = ez[k];
                float r2  = x * x + y * y + z * z;
                float inv = 1.0f / r2;
                float c6  = inv * inv * inv;
                float c12 = c6 * c6;
                esum += 2.0f * (c12 - c6) + HALF_NEG_E0;
                float fs = -24.0f * (2.0f * c12 - c6) * inv * FPSCALE;
                int ix = __float2int_rn(fs * x);
                int iy = __float2int_rn(fs * y);
                int iz = __float2int_rn(fs * z);
                int b  = ((unsigned)dd[k]) >> SHIFT;
                int slot = atomicAdd(&lcur[b], 1);
                s_ent[slot] = make_int2((ix & 0xffff) | (iy << 16),
                                        (iz & 0xffff) | ((dd[k] & (BK - 1)) << 16));
                s_bkt[slot] = (unsigned char)b;
            }
        }
        __syncthreads();

        // flush: bucket order -> contiguous runs
        const int nloc = max(0, min(E, ge << 2) - (gs << 2));
        for (int i = t; i < nloc; i += T) {
            int2 e = s_ent[i];
            sorted[gml[(int)s_bkt[i]] + i] = e;
        }
    }

    // per-block energy -> eblk (plain store, deterministic)
#pragma unroll
    for (int off = 32; off > 0; off >>= 1)
        esum += __shfl_down(esum, off, 64);
    __syncthreads();
    if ((t & 63) == 0) wsum[t >> 6] = esum;
    __syncthreads();
    if (t == 0) {
        float s = 0.0f;
        for (int w = 0; w < T / 64; ++w) s += wsum[w];
        eblk[blockIdx.x] = s;
    }

    grid.sync();

    // ---- phase 4a: per-(bucket, sub-chunk) partial reduce ------------------
    {
        unsigned long long* accXY = (unsigned long long*)smem;  // [BK] 8KB
        int* accZ = smem + 2 * BK;                              // [BK] 4KB
        const int S2 = 1 << QS;
        const int NT = NB << QS;
        for (int task = blockIdx.x; task < NT; task += gridDim.x) {
            __syncthreads();                 // prev task's store done
            const int b = task >> QS;
            const int q = task & (S2 - 1);
            for (int i = t; i < BK; i += T) { accXY[i] = 0ull; accZ[i] = 0; }
            __syncthreads();
            const unsigned len = gcur[b];
            const unsigned s0  = (unsigned)b * (unsigned)cap;
            unsigned chunk = (((len + S2 - 1) >> QS) + 1) & ~1u;
            const unsigned c0 = min(len, (unsigned)q * chunk);
            const unsigned c1 = min(len, c0 + chunk);

            auto acc2 = [&](int4 v) {
                int lid0 = ((unsigned)v.y) >> 16;
                unsigned long long p0 =
                    ((unsigned long long)(unsigned)(v.x >> 16) << 32)
                  + (unsigned long long)(long long)(int)(short)(v.x & 0xffff);
                atomicAdd(&accXY[lid0], p0);
                atomicAdd(&accZ[lid0], (int)(short)(v.y & 0xffff));
                int lid1 = ((unsigned)v.w) >> 16;
                unsigned long long p1 =
                    ((unsigned long long)(unsigned)(v.z >> 16) << 32)
                  + (unsigned long long)(long long)(int)(short)(v.z & 0xffff);
                atomicAdd(&accXY[lid1], p1);
                atomicAdd(&accZ[lid1], (int)(short)(v.w & 0xffff));
            };

            unsigned base = c0 + 2 * threadIdx.x;
            for (; base + 6 * T + 1 < c1; base += 8 * T) {
                int4 v0 = *(const int4*)(sorted + s0 + base);
                int4 v1 = *(const int4*)(sorted + s0 + base + 2 * T);
                int4 v2 = *(const int4*)(sorted + s0 + base + 4 * T);
                int4 v3 = *(const int4*)(sorted + s0 + base + 6 * T);
                acc2(v0); acc2(v1); acc2(v2); acc2(v3);
            }
            for (; base < c1; base += 2 * T) {
                if (base + 1 < c1) acc2(*(const int4*)(sorted + s0 + base));
                else {
                    int2 v = sorted[s0 + base];
                    int lid0 = ((unsigned)v.y) >> 16;
                    unsigned long long p0 =
                        ((unsigned long long)(unsigned)(v.x >> 16) << 32)
                      + (unsigned long long)(long long)(int)(short)(v.x & 0xffff);
                    atomicAdd(&accXY[lid0], p0);
                    atomicAdd(&accZ[lid0], (int)(short)(v.y & 0xffff));
                }
            }
            __syncthreads();
            unsigned long long* PX = partXY + (size_t)task * BK;
            int*                PZ = partZ  + (size_t)task * BK;
            for (int i = t; i < BK; i += T) { PX[i] = accXY[i]; PZ[i] = accZ[i]; }
        }
    }

    grid.sync();

    // ---- phase 4b: deterministic energy + merge partials -> outputs --------
    if (blockIdx.x == 0) {
        float es = 0.0f;
        for (int i = t; i < (int)gridDim.x; i += T) es += eblk[i];
#pragma unroll
        for (int off = 32; off > 0; off >>= 1)
            es += __shfl_down(es, off, 64);
        __syncthreads();
        if ((t & 63) == 0) wsum[t >> 6] = es;
        __syncthreads();
        if (t == 0) {
            float s = 0.0f;
            for (int w = 0; w < T / 64; ++w) s += wsum[w];
            energy[0] = s;
        }
    }
    {
        const int S2 = 1 << QS;
        for (int node = blockIdx.x * T + t; node < N; node += gridDim.x * T) {
            const int b   = node >> SHIFT;
            const int lid = node & (BK - 1);
            const unsigned long long* PX = partXY + ((size_t)(b << QS)) * BK + lid;
            const int*                PZ = partZ  + ((size_t)(b << QS)) * BK + lid;
            unsigned long long sxy = 0ull; int sz = 0;
#pragma unroll
            for (int q = 0; q < S2; ++q) {
                sxy += PX[(size_t)q * BK];
                sz  += PZ[(size_t)q * BK];
            }
            int sx = (int)(unsigned)(sxy & 0xffffffffull);
            int sy = (int)(unsigned)(sxy >> 32) + (sx < 0 ? 1 : 0);
            float vx = (float)sx * INV_FPSCALE;
            float vy = (float)sy * INV_FPSCALE;
            float vz = (float)sz * INV_FPSCALE;
            analytic[3 * node + 0] = vx;
            analytic[3 * node + 1] = vy;
            analytic[3 * node + 2] = vz;
            forces[3 * node + 0] = -0.5f * vx;
            forces[3 * node + 1] = -0.5f * vy;
            forces[3 * node + 2] = -0.5f * vz;
        }
    }
}

// ==================== legacy 3-kernel path (R7, proven) =====================
__global__ __launch_bounds__(T)
void p3_fused(const float* __restrict__ bv, const int* __restrict__ dst,
              unsigned* __restrict__ gcur, int2* __restrict__ sorted,
              float* __restrict__ energy, int E, int NB, int GPBv, int cap)
{
    extern __shared__ int smem[];
    const int capb = GPBv << 2;
    int2*          s_ent = (int2*)smem;
    unsigned char* s_bkt = (unsigned char*)(smem + 2 * capb);
    int* lcur = smem + 2 * capb + (capb + 3) / 4;
    int* gml  = lcur + NB;

    const int r = blockIdx.x;
    const int t = threadIdx.x;

    for (int b = t; b < NB; b += T) lcur[b] = 0;
    __syncthreads();

    const int G  = (E + 3) >> 2;
    const int gs = r * GPBv;
    const int ge = min(G, gs + GPBv);
    const int4* __restrict__ d4 = (const int4*)dst;

    for (int g = gs + t; g < ge; g += T) {
        const int e0 = g << 2;
        if (e0 + 3 < E) {
            int4 d = d4[g];
            atomicAdd(&lcur[((unsigned)d.x) >> SHIFT], 1);
            atomicAdd(&lcur[((unsigned)d.y) >> SHIFT], 1);
            atomicAdd(&lcur[((unsigned)d.z) >> SHIFT], 1);
            atomicAdd(&lcur[((unsigned)d.w) >> SHIFT], 1);
        } else {
            for (int e = e0; e < E; ++e)
                atomicAdd(&lcur[((unsigned)dst[e]) >> SHIFT], 1);
        }
    }
    __syncthreads();

    int* sc = (int*)s_ent;
    if (t < 128) sc[t] = (t < NB) ? lcur[t] : 0;
    __syncthreads();
#pragma unroll
    for (int off = 1; off < 128; off <<= 1) {
        int a0 = (t < 128 && t >= off) ? sc[t - off] : 0;
        __syncthreads();
        if (t < 128) sc[t] += a0;
        __syncthreads();
    }
    if (t < NB) {
        int cnt = lcur[t];
        int ex  = sc[t] - cnt;
        unsigned ret = atomicAdd(&gcur[t], (unsigned)cnt);
        gml[t]  = t * cap + (int)ret - ex;
        lcur[t] = ex;
    }
    __syncthreads();

    const float4* __restrict__ bv4 = (const float4*)bv;
    float esum = 0.0f;

    for (int g = gs + t; g < ge; g += T) {
        const int e0 = g << 2;
        float ex4[4], ey[4], ez[4]; int dd[4];
        int nk;
        if (e0 + 3 < E) {
            float4 a  = bv4[3 * g + 0];
            float4 b2 = bv4[3 * g + 1];
            float4 c  = bv4[3 * g + 2];
            int4 d = d4[g];
            ex4[0] = a.x;  ey[0] = a.y;  ez[0] = a.z;
            ex4[1] = a.w;  ey[1] = b2.x; ez[1] = b2.y;
            ex4[2] = b2.z; ey[2] = b2.w; ez[2] = c.x;
            ex4[3] = c.y;  ey[3] = c.z;  ez[3] = c.w;
            dd[0] = d.x; dd[1] = d.y; dd[2] = d.z; dd[3] = d.w;
            nk = 4;
        } else {
            nk = E - e0;
            for (int k = 0; k < nk; ++k) {
                ex4[k] = bv[3 * (e0 + k) + 0];
                ey[k]  = bv[3 * (e0 + k) + 1];
                ez[k]  = bv[3 * (e0 + k) + 2];
                dd[k]  = dst[e0 + k];
            }
        }
        for (int k = 0; k < nk; ++k) {
            float x = ex4[k], y = ey[k], z = ez[k];
            float r2  = x * x + y * y + z * z;
            float inv = 1.0f / r2;
            float c6  = inv * inv * inv;
            float c12 = c6 * c6;
            esum += 2.0f * (c12 - c6) + HALF_NEG_E0;
            float fs = -24.0f * (2.0f * c12 - c6) * inv * FPSCALE;
            int ix = __float2int_rn(fs * x);
            int iy = __float2int_rn(fs * y);
            int iz = __float2int_rn(fs * z);
            int b  = ((unsigned)dd[k]) >> SHIFT;
            int slot = atomicAdd(&lcur[b], 1);
            s_ent[slot] = make_int2((ix & 0xffff) | (iy << 16),
                                    (iz & 0xffff) | ((dd[k] & (BK - 1)) << 16));
            s_bkt[slot] = (unsigned char)b;
        }
    }
    __syncthreads();

    const int nloc = max(0, min(E, ge << 2) - (gs << 2));
    for (int i = t; i < nloc; i += T) {
        int2 e = s_ent[i];
        sorted[gml[(int)s_bkt[i]] + i] = e;
    }

#pragma unroll
    for (int off = 32; off > 0; off >>= 1)
        esum += __shfl_down(esum, off, 64);
    __shared__ float wsum[T / 64];
    const int wid = t >> 6, lid = t & 63;
    if (lid == 0) wsum[wid] = esum;
    __syncthreads();
    if (t == 0) {
        float s = 0.0f;
        for (int w = 0; w < T / 64; ++w) s += wsum[w];
        unsafeAtomicAdd(energy, s);
    }
}

__global__ __launch_bounds__(T)
void p4a_partial(const int2* __restrict__ sorted, const unsigned* __restrict__ gcur,
                 unsigned long long* __restrict__ partXY, int* __restrict__ partZ,
                 int cap)
{
    __shared__ unsigned long long accXY[BK];
    __shared__ int accZ[BK];
    const int S2 = 1 << QS;
    const int b = blockIdx.x >> QS;
    const int q = blockIdx.x & (S2 - 1);
    for (int t = threadIdx.x; t < BK; t += T) { accXY[t] = 0ull; accZ[t] = 0; }
    __syncthreads();
    const unsigned len = gcur[b];
    const unsigned s0  = (unsigned)b * (unsigned)cap;
    unsigned chunk = (((len + S2 - 1) >> QS) + 1) & ~1u;
    const unsigned c0 = min(len, (unsigned)q * chunk);
    const unsigned c1 = min(len, c0 + chunk);

    auto acc2 = [&](int4 v) {
        int lid0 = ((unsigned)v.y) >> 16;
        unsigned long long p0 = ((unsigned long long)(unsigned)(v.x >> 16) << 32)
                              + (unsigned long long)(long long)(int)(short)(v.x & 0xffff);
        atomicAdd(&accXY[lid0], p0);
        atomicAdd(&accZ[lid0], (int)(short)(v.y & 0xffff));
        int lid1 = ((unsigned)v.w) >> 16;
        unsigned long long p1 = ((unsigned long long)(unsigned)(v.z >> 16) << 32)
                              + (unsigned long long)(long long)(int)(short)(v.z & 0xffff);
        atomicAdd(&accXY[lid1], p1);
        atomicAdd(&accZ[lid1], (int)(short)(v.w & 0xffff));
    };

    unsigned base = c0 + 2 * threadIdx.x;
    for (; base + 6 * T + 1 < c1; base += 8 * T) {
        int4 v0 = *(const int4*)(sorted + s0 + base);
        int4 v1 = *(const int4*)(sorted + s0 + base + 2 * T);
        int4 v2 = *(const int4*)(sorted + s0 + base + 4 * T);
        int4 v3 = *(const int4*)(sorted + s0 + base + 6 * T);
        acc2(v0); acc2(v1); acc2(v2); acc2(v3);
    }
    for (; base < c1; base += 2 * T) {
        if (base + 1 < c1) acc2(*(const int4*)(sorted + s0 + base));
        else {
            int2 v = sorted[s0 + base];
            int lid0 = ((unsigned)v.y) >> 16;
            unsigned long long p0 = ((unsigned long long)(unsigned)(v.x >> 16) << 32)
                                  + (unsigned long long)(long long)(int)(short)(v.x & 0xffff);
            atomicAdd(&accXY[lid0], p0);
            atomicAdd(&accZ[lid0], (int)(short)(v.y & 0xffff));
        }
    }
    __syncthreads();
    unsigned long long* PX = partXY + (size_t)blockIdx.x * BK;
    int*                PZ = partZ  + (size_t)blockIdx.x * BK;
    for (int t = threadIdx.x; t < BK; t += T) { PX[t] = accXY[t]; PZ[t] = accZ[t]; }
}

__global__ __launch_bounds__(T)
void p4b_merge(const unsigned long long* __restrict__ partXY,
               const int* __restrict__ partZ,
               float* __restrict__ forces, float* __restrict__ analytic, int N)
{
    const int node = blockIdx.x * T + threadIdx.x;
    if (node >= N) return;
    const int b   = node >> SHIFT;
    const int lid = node & (BK - 1);
    const int S2  = 1 << QS;
    const unsigned long long* PX = partXY + ((size_t)(b << QS)) * BK + lid;
    const int*                PZ = partZ  + ((size_t)(b << QS)) * BK + lid;
    unsigned long long sxy = 0ull; int sz = 0;
#pragma unroll
    for (int q = 0; q < S2; ++q) {
        sxy += PX[(size_t)q * BK];
        sz  += PZ[(size_t)q * BK];
    }
    int sx = (int)(unsigned)(sxy & 0xffffffffull);
    int sy = (int)(unsigned)(sxy >> 32) + (sx < 0 ? 1 : 0);
    float vx = (float)sx * INV_FPSCALE;
    float vy = (float)sy * INV_FPSCALE;
    float vz = (float)sz * INV_FPSCALE;
    analytic[3 * node + 0] = vx;
    analytic[3 * node + 1] = vy;
    analytic[3 * node + 2] = vz;
    forces[3 * node + 0] = -0.5f * vx;
    forces[3 * node + 1] = -0.5f * vy;
    forces[3 * node + 2] = -0.5f * vz;
}

__global__ __launch_bounds__(T)
void lj_fallback(const float* __restrict__ bv, const int* __restrict__ dst,
                 float* __restrict__ out_energy, float* __restrict__ analytic, int E)
{
    const int e = blockIdx.x * blockDim.x + threadIdx.x;
    float esum = 0.0f;
    if (e < E) {
        float x = bv[3 * e], y = bv[3 * e + 1], z = bv[3 * e + 2];
        float r2 = x * x + y * y + z * z;
        float inv = 1.0f / r2;
        float c6 = inv * inv * inv, c12 = c6 * c6;
        esum = 2.0f * (c12 - c6) + HALF_NEG_E0;
        float fs = -24.0f * (2.0f * c12 - c6) * inv;
        float* p = analytic + 3 * (size_t)dst[e];
        unsafeAtomicAdd(p + 0, fs * x);
        unsafeAtomicAdd(p + 1, fs * y);
        unsafeAtomicAdd(p + 2, fs * z);
    }
#pragma unroll
    for (int off = 32; off > 0; off >>= 1) esum += __shfl_down(esum, off, 64);
    __shared__ float wsum[T / 64];
    if ((threadIdx.x & 63) == 0) wsum[threadIdx.x >> 6] = esum;
    __syncthreads();
    if (threadIdx.x == 0) {
        float s = 0.0f;
        for (int w = 0; w < T / 64; ++w) s += wsum[w];
        unsafeAtomicAdd(out_energy, s);
    }
}

__global__ __launch_bounds__(T)
void lj_scale(const float* __restrict__ analytic, float* __restrict__ forces, int n)
{
    int i = blockIdx.x * blockDim.x + threadIdx.x;
    if (i < n) forces[i] = -0.5f * analytic[i];
}

extern "C" void kernel_launch(void* const* d_in, const int* in_sizes, int n_in,
                              void* d_out, int out_size, void* d_ws, size_t ws_size,
                              hipStream_t stream)
{
    const float* bv  = (const float*)d_in[0];
    const int*   dst = (const int*)d_in[1];
    const int E = in_sizes[0] / 3;
    const int N = (out_size - 1) / 6;   // out = [energy | forces(3N) | analytic(3N)]
    if (E <= 0 || N <= 0) return;

    float* out      = (float*)d_out;
    float* energy   = out;
    float* forces   = out + 1;
    float* analytic = out + 1 + (size_t)3 * N;

    const int NB = (N + BK - 1) / BK;
    const int G  = (E + 3) / 4;

    // per-bucket region capacity: mean + 10 sigma + 64, rounded even
    const int avg = E / NB;
    int cap = avg + 10 * (int)ceil(sqrt((double)avg)) + 64;
    cap = (cap + 1) & ~1;

    auto al = [](size_t x) { return (x + 255) & ~(size_t)255; };
    const size_t sorted_bytes = al((size_t)NB * cap * 8);
    const size_t gcur_bytes   = al((size_t)NB * 4);
    const size_t eblk_bytes   = al((size_t)MAXBLK * 4);
    const size_t partXY_bytes = al((size_t)NB * (1 << QS) * BK * 8);
    const size_t partZ_bytes  = al((size_t)NB * (1 << QS) * BK * 4);
    const size_t need = sorted_bytes + gcur_bytes + eblk_bytes
                      + partXY_bytes + partZ_bytes;

    // one-time cooperative capability + occupancy query (host-only, capture-safe)
    static int s_coop = -1;
    static int s_nblocks = 0;
    if (s_coop < 0) {
        int dev = 0, coop = 0, ncu = 0, perCU = 0;
        hipError_t e0 = hipGetDevice(&dev);
        hipError_t e1 = hipDeviceGetAttribute(&coop,
                            hipDeviceAttributeCooperativeLaunch, dev);
        hipError_t e2 = hipDeviceGetAttribute(&ncu,
                            hipDeviceAttributeMultiprocessorCount, dev);
        hipError_t e3 = hipOccupancyMaxActiveBlocksPerMultiprocessor(
                            &perCU, lj_coop, T, (size_t)SMEM_BYTES);
        if (e0 == hipSuccess && e1 == hipSuccess && e2 == hipSuccess &&
            e3 == hipSuccess && coop && ncu > 0 && perCU > 0) {
            s_coop = 1;
            int nb = perCU * ncu;
            s_nblocks = nb < MAXBLK ? nb : MAXBLK;
        } else {
            s_coop = 0;
        }
    }

    if (s_coop == 1 && NB <= 128 && ws_size >= need) {
        char* w = (char*)d_ws;
        int2*               sorted = (int2*)w;               w += sorted_bytes;
        unsigned*           gcur   = (unsigned*)w;           w += gcur_bytes;
        float*              eblk   = (float*)w;              w += eblk_bytes;
        unsigned long long* partXY = (unsigned long long*)w; w += partXY_bytes;
        int*                partZ  = (int*)w;

        int nblocks = s_nblocks;
        int nchunks = (G + nblocks * GPB - 1) / (nblocks * GPB);

        void* args[] = { (void*)&bv, (void*)&dst, (void*)&gcur, (void*)&sorted,
                         (void*)&eblk, (void*)&partXY, (void*)&partZ,
                         (void*)&forces, (void*)&analytic, (void*)&energy,
                         (void*)&E, (void*)&N, (void*)&NB, (void*)&cap,
                         (void*)&nchunks };
        hipError_t le = hipLaunchCooperativeKernel(lj_coop, dim3(nblocks), dim3(T),
                                                   args, (unsigned)SMEM_BYTES,
                                                   stream);
        if (le == hipSuccess) return;
        // fall through to legacy path on launch/capture rejection
    }

    // -------------------- legacy path (proven, 5 dispatches) ----------------
    const int GPBv = (G + B1 - 1) / B1;
    const int capb = GPBv * 4;
    const size_t smem_bytes = (size_t)capb * 8 + ((size_t)(capb + 3) / 4) * 4
                            + (size_t)2 * NB * 4;
    const size_t need_legacy = sorted_bytes + gcur_bytes
                             + partXY_bytes + partZ_bytes;

    if (NB <= 128 && capb >= 128 && smem_bytes <= 64000 && ws_size >= need_legacy) {
        char* w = (char*)d_ws;
        int2*               sorted = (int2*)w;               w += sorted_bytes;
        unsigned*           gcur   = (unsigned*)w;           w += gcur_bytes;
        unsigned long long* partXY = (unsigned long long*)w; w += partXY_bytes;
        int*                partZ  = (int*)w;

        hipMemsetAsync(gcur, 0, (size_t)NB * 4, stream);
        hipMemsetAsync(energy, 0, sizeof(float), stream);
        p3_fused   <<<B1, T, smem_bytes, stream>>>(bv, dst, gcur, sorted, energy,
                                                   E, NB, GPBv, cap);
        p4a_partial<<<NB << QS, T, 0, stream>>>(sorted, gcur, partXY, partZ, cap);
        p4b_merge  <<<(N + T - 1) / T, T, 0, stream>>>(partXY, partZ,
                                                       forces, analytic, N);
    } else {
        hipMemsetAsync(d_out, 0, (size_t)out_size * sizeof(float), stream);
        lj_fallback<<<(E + T - 1) / T, T, 0, stream>>>(bv, dst, energy, analytic, E);
        const int n3 = 3 * N;
        lj_scale<<<(n3 + T - 1) / T, T, 0, stream>>>(analytic, forces, n3);
    }
}

// Round 9
// 264.925 us; speedup vs baseline: 1.7895x; 1.7895x over previous
//
#include <hip/hip_runtime.h>
#include <math.h>

// e0 = 4*((1/3)^12 - (1/3)^6); 0.5*pe = 2*(c12 - c6) - 0.5*e0
static constexpr float HALF_NEG_E0 = 2.739720872e-3f; // -0.5*e0

#define T 256           // threads per block
#define B1 2500         // blocks for p3 (fixed: bmap/runs sized to this)
#define SHIFT 9
#define NPB 512         // nodes per bucket (lid fits in 9 bits)
#define FPSCALE 512.0f  // |f| <= 59.5 -> |int| <= 30450 < 32767
#define INV_FPSCALE (1.0f / 512.0f)

// ---- Phase 3: deterministic staging. Per block: histogram -> 256-wide scan
//      -> bucket-grouped LDS staging -> contiguous coalesced flush to own
//      region sorted[r*capb ..]. Run directory bmap[r][b] = ex | (cnt<<16).
//      NO global atomics, NO memset dependency. Energy -> eblk[r] plain store.
__global__ __launch_bounds__(T)
void p3_fused(const float* __restrict__ bv, const int* __restrict__ dst,
              int* __restrict__ bmap, int2* __restrict__ sorted,
              float* __restrict__ eblk, int E, int NB, int GPB, int capb)
{
    extern __shared__ int smem[];
    int2*          s_ent = (int2*)smem;                       // [capb]
    unsigned char* s_bkt = (unsigned char*)(smem + 2 * capb); // [capb]
    int* lcur = smem + 2 * capb + (capb + 3) / 4;             // [NB]

    const int r = blockIdx.x;
    const int t = threadIdx.x;

    for (int b = t; b < NB; b += T) lcur[b] = 0;
    __syncthreads();

    const int G  = (E + 3) >> 2;
    const int gs = r * GPB;
    const int ge = min(G, gs + GPB);
    const int4* __restrict__ d4 = (const int4*)dst;

    // ---- pass A: local bucket histogram (native LDS int atomics) -----------
    for (int g = gs + t; g < ge; g += T) {
        const int e0 = g << 2;
        if (e0 + 3 < E) {
            int4 d = d4[g];
            atomicAdd(&lcur[((unsigned)d.x) >> SHIFT], 1);
            atomicAdd(&lcur[((unsigned)d.y) >> SHIFT], 1);
            atomicAdd(&lcur[((unsigned)d.z) >> SHIFT], 1);
            atomicAdd(&lcur[((unsigned)d.w) >> SHIFT], 1);
        } else {
            for (int e = e0; e < E; ++e)
                atomicAdd(&lcur[((unsigned)dst[e]) >> SHIFT], 1);
        }
    }
    __syncthreads();

    // ---- 256-wide exclusive scan of local counts (NB <= 256) ---------------
    int* sc = (int*)s_ent;                        // reuse staging (256 ints)
    sc[t] = (t < NB) ? lcur[t] : 0;
    __syncthreads();
#pragma unroll
    for (int off = 1; off < 256; off <<= 1) {
        int a0 = (t >= off) ? sc[t - off] : 0;
        __syncthreads();
        sc[t] += a0;
        __syncthreads();
    }
    // ---- write run directory; lcur becomes slot cursor ---------------------
    if (t < NB) {
        int cnt = lcur[t];
        int ex  = sc[t] - cnt;                    // exclusive prefix
        bmap[(size_t)r * NB + t] = ex | (cnt << 16);
        lcur[t] = ex;
    }
    __syncthreads();

    // ---- pass B: compute forces + energy, stage bucket-grouped -------------
    const float4* __restrict__ bv4 = (const float4*)bv;
    float esum = 0.0f;

    for (int g = gs + t; g < ge; g += T) {
        const int e0 = g << 2;
        float ex4[4], ey[4], ez[4]; int dd[4];
        int nk;
        if (e0 + 3 < E) {
            float4 a  = bv4[3 * g + 0];
            float4 b2 = bv4[3 * g + 1];
            float4 c  = bv4[3 * g + 2];
            int4 d = d4[g];
            ex4[0] = a.x;  ey[0] = a.y;  ez[0] = a.z;
            ex4[1] = a.w;  ey[1] = b2.x; ez[1] = b2.y;
            ex4[2] = b2.z; ey[2] = b2.w; ez[2] = c.x;
            ex4[3] = c.y;  ey[3] = c.z;  ez[3] = c.w;
            dd[0] = d.x; dd[1] = d.y; dd[2] = d.z; dd[3] = d.w;
            nk = 4;
        } else {
            nk = E - e0;
            for (int k = 0; k < nk; ++k) {
                ex4[k] = bv[3 * (e0 + k) + 0];
                ey[k]  = bv[3 * (e0 + k) + 1];
                ez[k]  = bv[3 * (e0 + k) + 2];
                dd[k]  = dst[e0 + k];
            }
        }
        for (int k = 0; k < nk; ++k) {
            float x = ex4[k], y = ey[k], z = ez[k];
            float r2  = x * x + y * y + z * z;
            float inv = 1.0f / r2;
            float c6  = inv * inv * inv;
            float c12 = c6 * c6;
            esum += 2.0f * (c12 - c6) + HALF_NEG_E0;
            float fs = -24.0f * (2.0f * c12 - c6) * inv * FPSCALE;
            int ix = __float2int_rn(fs * x);
            int iy = __float2int_rn(fs * y);
            int iz = __float2int_rn(fs * z);
            int b  = ((unsigned)dd[k]) >> SHIFT;
            int slot = atomicAdd(&lcur[b], 1);    // native LDS int atomic
            s_ent[slot] = make_int2((ix & 0xffff) | (iy << 16),
                                    (iz & 0xffff) | ((dd[k] & (NPB - 1)) << 16));
            s_bkt[slot] = (unsigned char)b;
        }
    }
    __syncthreads();

    // ---- flush: contiguous coalesced write to own region -------------------
    const int nloc = max(0, min(E, ge << 2) - (gs << 2));
    for (int i = t; i < nloc; i += T)
        sorted[(size_t)r * capb + i] = s_ent[i];

    // ---- energy: wave shuffle -> LDS -> one plain store per block ----------
#pragma unroll
    for (int off = 32; off > 0; off >>= 1)
        esum += __shfl_down(esum, off, 64);
    __shared__ float wsum[T / 64];
    const int wid = t >> 6, lid = t & 63;
    if (lid == 0) wsum[wid] = esum;
    __syncthreads();
    if (t == 0) {
        float s = 0.0f;
        for (int w = 0; w < T / 64; ++w) s += wsum[w];
        eblk[r] = s;
    }
}

// ---- Phase 4 (fused a+b): one block per bucket. Gather this bucket's run
//      from each p3-block region (wave-per-run, 4-deep MLP), accumulate in
//      LDS (packed u64 XY + int Z), decode, write outputs directly.
//      Block 0 additionally reduces eblk -> energy. Fully deterministic.
__global__ __launch_bounds__(T)
void p4ab(const int2* __restrict__ sorted, const int* __restrict__ bmap,
          const float* __restrict__ eblk,
          float* __restrict__ forces, float* __restrict__ analytic,
          float* __restrict__ energy, int N, int NB, int nblk, int capb)
{
    __shared__ int runs[B1];                      // 10 KB
    __shared__ unsigned long long accXY[NPB];     // 4 KB
    __shared__ int accZ[NPB];                     // 2 KB
    __shared__ float ws[T / 64];

    const int b = blockIdx.x;
    const int t = threadIdx.x;

    for (int i = t; i < NPB; i += T) { accXY[i] = 0ull; accZ[i] = 0; }
    for (int i = t; i < nblk; i += T) runs[i] = bmap[(size_t)i * NB + b];
    __syncthreads();

    const int wid = t >> 6, lane = t & 63;

    auto accv = [&](int2 v) {
        int lid = ((unsigned)v.y) >> 16;
        unsigned long long p =
            ((unsigned long long)(unsigned)(v.x >> 16) << 32)
          + (unsigned long long)(long long)(int)(short)(v.x & 0xffff);
        atomicAdd(&accXY[lid], p);
        atomicAdd(&accZ[lid], (int)(short)(v.y & 0xffff));
    };

    // wave-per-run over contiguous r-range; 4 runs grouped for MLP
    const int per = (nblk + 3) >> 2;
    const int r0 = wid * per;
    const int r1 = min(nblk, r0 + per);
    int r = r0;
    for (; r + 3 < r1; r += 4) {
        int m0 = runs[r + 0], m1 = runs[r + 1], m2 = runs[r + 2], m3 = runs[r + 3];
        int c0 = m0 >> 16, c1 = m1 >> 16, c2 = m2 >> 16, c3 = m3 >> 16;
        const int2* s0 = sorted + (size_t)(r + 0) * capb + (m0 & 0xffff);
        const int2* s1 = sorted + (size_t)(r + 1) * capb + (m1 & 0xffff);
        const int2* s2 = sorted + (size_t)(r + 2) * capb + (m2 & 0xffff);
        const int2* s3 = sorted + (size_t)(r + 3) * capb + (m3 & 0xffff);
        int2 v0 = {0,0}, v1 = {0,0}, v2 = {0,0}, v3 = {0,0};
        bool f0 = lane < c0, f1 = lane < c1, f2 = lane < c2, f3 = lane < c3;
        if (f0) v0 = s0[lane];
        if (f1) v1 = s1[lane];
        if (f2) v2 = s2[lane];
        if (f3) v3 = s3[lane];
        if (f0) accv(v0);
        if (f1) accv(v1);
        if (f2) accv(v2);
        if (f3) accv(v3);
        // rare long-run tails (cnt > 64)
        for (int c = lane + 64; c < c0; c += 64) accv(s0[c]);
        for (int c = lane + 64; c < c1; c += 64) accv(s1[c]);
        for (int c = lane + 64; c < c2; c += 64) accv(s2[c]);
        for (int c = lane + 64; c < c3; c += 64) accv(s3[c]);
    }
    for (; r < r1; ++r) {
        int m = runs[r];
        int cnt = m >> 16;
        const int2* src = sorted + (size_t)r * capb + (m & 0xffff);
        for (int c = lane; c < cnt; c += 64) accv(src[c]);
    }
    __syncthreads();

    // energy reduce (block 0 only; block-uniform branch)
    if (b == 0) {
        float es = 0.0f;
        for (int i = t; i < nblk; i += T) es += eblk[i];
#pragma unroll
        for (int off = 32; off > 0; off >>= 1)
            es += __shfl_down(es, off, 64);
        if (lane == 0) ws[wid] = es;
        __syncthreads();
        if (t == 0) {
            float s = 0.0f;
            for (int w = 0; w < T / 64; ++w) s += ws[w];
            energy[0] = s;
        }
    }

    // decode + write outputs for this bucket's nodes
    const int node0 = b << SHIFT;
    for (int i = t; i < NPB; i += T) {
        const int node = node0 + i;
        if (node < N) {
            unsigned long long sxy = accXY[i];
            int sx = (int)(unsigned)(sxy & 0xffffffffull);
            int sy = (int)(unsigned)(sxy >> 32) + (sx < 0 ? 1 : 0);
            int sz = accZ[i];
            float vx = (float)sx * INV_FPSCALE;
            float vy = (float)sy * INV_FPSCALE;
            float vz = (float)sz * INV_FPSCALE;
            analytic[3 * node + 0] = vx;
            analytic[3 * node + 1] = vy;
            analytic[3 * node + 2] = vz;
            forces[3 * node + 0] = -0.5f * vx;
            forces[3 * node + 1] = -0.5f * vy;
            forces[3 * node + 2] = -0.5f * vz;
        }
    }
}

// ---------------- Fallback if workspace/shape unsupported -------------------
__global__ __launch_bounds__(T)
void lj_fallback(const float* __restrict__ bv, const int* __restrict__ dst,
                 float* __restrict__ out_energy, float* __restrict__ analytic, int E)
{
    const int e = blockIdx.x * blockDim.x + threadIdx.x;
    float esum = 0.0f;
    if (e < E) {
        float x = bv[3 * e], y = bv[3 * e + 1], z = bv[3 * e + 2];
        float r2 = x * x + y * y + z * z;
        float inv = 1.0f / r2;
        float c6 = inv * inv * inv, c12 = c6 * c6;
        esum = 2.0f * (c12 - c6) + HALF_NEG_E0;
        float fs = -24.0f * (2.0f * c12 - c6) * inv;
        float* p = analytic + 3 * (size_t)dst[e];
        unsafeAtomicAdd(p + 0, fs * x);
        unsafeAtomicAdd(p + 1, fs * y);
        unsafeAtomicAdd(p + 2, fs * z);
    }
#pragma unroll
    for (int off = 32; off > 0; off >>= 1) esum += __shfl_down(esum, off, 64);
    __shared__ float wsum[T / 64];
    if ((threadIdx.x & 63) == 0) wsum[threadIdx.x >> 6] = esum;
    __syncthreads();
    if (threadIdx.x == 0) {
        float s = 0.0f;
        for (int w = 0; w < T / 64; ++w) s += wsum[w];
        unsafeAtomicAdd(out_energy, s);
    }
}

__global__ __launch_bounds__(T)
void lj_scale(const float* __restrict__ analytic, float* __restrict__ forces, int n)
{
    int i = blockIdx.x * blockDim.x + threadIdx.x;
    if (i < n) forces[i] = -0.5f * analytic[i];
}

extern "C" void kernel_launch(void* const* d_in, const int* in_sizes, int n_in,
                              void* d_out, int out_size, void* d_ws, size_t ws_size,
                              hipStream_t stream)
{
    const float* bv  = (const float*)d_in[0];
    const int*   dst = (const int*)d_in[1];
    const int E = in_sizes[0] / 3;
    const int N = (out_size - 1) / 6;   // out = [energy | forces(3N) | analytic(3N)]
    if (E <= 0 || N <= 0) return;

    float* out      = (float*)d_out;
    float* energy   = out;
    float* forces   = out + 1;
    float* analytic = out + 1 + (size_t)3 * N;

    const int NB  = (N + NPB - 1) / NPB;
    const int G   = (E + 3) / 4;
    const int GPB = (G + B1 - 1) / B1;
    const int capb = GPB * 4;

    auto al = [](size_t x) { return (x + 255) & ~(size_t)255; };
    const size_t sorted_bytes = al((size_t)B1 * capb * 8);
    const size_t bmap_bytes   = al((size_t)B1 * NB * 4);
    const size_t eblk_bytes   = al((size_t)B1 * 4);
    const size_t need = sorted_bytes + bmap_bytes + eblk_bytes;

    // smem ints: s_ent(2*capb) + s_bkt(ceil(capb/4)) + lcur(NB); scan sc
    // reuses s_ent (needs 256 ints -> capb >= 128).
    const size_t smem_bytes = (size_t)capb * 8 + ((size_t)(capb + 3) / 4) * 4
                            + (size_t)NB * 4;

    if (NB <= 255 && capb >= 128 && smem_bytes <= 64000 && ws_size >= need) {
        char* w = (char*)d_ws;
        int2*  sorted = (int2*)w;  w += sorted_bytes;
        int*   bmap   = (int*)w;   w += bmap_bytes;
        float* eblk   = (float*)w;

        p3_fused<<<B1, T, smem_bytes, stream>>>(bv, dst, bmap, sorted, eblk,
                                                E, NB, GPB, capb);
        p4ab    <<<NB, T, 0, stream>>>(sorted, bmap, eblk, forces, analytic,
                                       energy, N, NB, B1, capb);
    } else {
        hipMemsetAsync(d_out, 0, (size_t)out_size * sizeof(float), stream);
        lj_fallback<<<(E + T - 1) / T, T, 0, stream>>>(bv, dst, energy, analytic, E);
        const int n3 = 3 * N;
        lj_scale<<<(n3 + T - 1) / T, T, 0, stream>>>(analytic, forces, n3);
    }
}

// Round 10
// 171.296 us; speedup vs baseline: 2.7676x; 1.5466x over previous
//
#include <hip/hip_runtime.h>
#include <math.h>

// e0 = 4*((1/3)^12 - (1/3)^6); 0.5*pe = 2*(c12 - c6) - 0.5*e0
static constexpr float HALF_NEG_E0 = 2.739720872e-3f; // -0.5*e0

#define T 256           // threads per block
#define B1 2500         // blocks for p3
#define SHIFT 10
#define BK 1024         // nodes per bucket (lid fits in 10 bits)
#define Q 8             // gather sub-blocks per bucket in p4a
#define RPQ_MAX 352     // max runs per p4a block (ceil(B1/Q)=313)
#define FPSCALE 512.0f  // |f| <= 59.5 -> |int| <= 30450 < 32767
#define INV_FPSCALE (1.0f / 512.0f)

// ---- Phase 3: deterministic staging (NO global atomics, NO memsets).
//      Per block: histogram -> 128-wide scan -> bucket-grouped LDS staging ->
//      contiguous coalesced flush to own region sorted[r*capb ..].
//      Run directory bmap[r][b] = ex | (cnt<<16). Energy -> eblk[r] store.
__global__ __launch_bounds__(T)
void p3_fused(const float* __restrict__ bv, const int* __restrict__ dst,
              int* __restrict__ bmap, int2* __restrict__ sorted,
              float* __restrict__ eblk, int E, int NB, int GPB, int capb)
{
    extern __shared__ int smem[];
    int2*          s_ent = (int2*)smem;                       // [capb]
    unsigned char* s_bkt = (unsigned char*)(smem + 2 * capb); // [capb]
    int* lcur = smem + 2 * capb + (capb + 3) / 4;             // [NB]

    const int r = blockIdx.x;
    const int t = threadIdx.x;

    for (int b = t; b < NB; b += T) lcur[b] = 0;
    __syncthreads();

    const int G  = (E + 3) >> 2;
    const int gs = r * GPB;
    const int ge = min(G, gs + GPB);
    const int4* __restrict__ d4 = (const int4*)dst;

    // ---- pass A: local bucket histogram (native LDS int atomics) -----------
    for (int g = gs + t; g < ge; g += T) {
        const int e0 = g << 2;
        if (e0 + 3 < E) {
            int4 d = d4[g];
            atomicAdd(&lcur[((unsigned)d.x) >> SHIFT], 1);
            atomicAdd(&lcur[((unsigned)d.y) >> SHIFT], 1);
            atomicAdd(&lcur[((unsigned)d.z) >> SHIFT], 1);
            atomicAdd(&lcur[((unsigned)d.w) >> SHIFT], 1);
        } else {
            for (int e = e0; e < E; ++e)
                atomicAdd(&lcur[((unsigned)dst[e]) >> SHIFT], 1);
        }
    }
    __syncthreads();

    // ---- 128-wide exclusive scan of local counts (NB <= 128) ---------------
    int* sc = (int*)s_ent;                        // reuse staging
    if (t < 128) sc[t] = (t < NB) ? lcur[t] : 0;
    __syncthreads();
#pragma unroll
    for (int off = 1; off < 128; off <<= 1) {
        int a0 = (t < 128 && t >= off) ? sc[t - off] : 0;
        __syncthreads();
        if (t < 128) sc[t] += a0;
        __syncthreads();
    }
    // ---- write run directory; lcur becomes slot cursor ---------------------
    if (t < NB) {
        int cnt = lcur[t];
        int ex  = sc[t] - cnt;                    // exclusive prefix
        bmap[(size_t)r * NB + t] = ex | (cnt << 16);
        lcur[t] = ex;
    }
    __syncthreads();

    // ---- pass B: compute forces + energy, stage bucket-grouped -------------
    const float4* __restrict__ bv4 = (const float4*)bv;
    float esum = 0.0f;

    for (int g = gs + t; g < ge; g += T) {
        const int e0 = g << 2;
        float ex4[4], ey[4], ez[4]; int dd[4];
        int nk;
        if (e0 + 3 < E) {
            float4 a  = bv4[3 * g + 0];
            float4 b2 = bv4[3 * g + 1];
            float4 c  = bv4[3 * g + 2];
            int4 d = d4[g];
            ex4[0] = a.x;  ey[0] = a.y;  ez[0] = a.z;
            ex4[1] = a.w;  ey[1] = b2.x; ez[1] = b2.y;
            ex4[2] = b2.z; ey[2] = b2.w; ez[2] = c.x;
            ex4[3] = c.y;  ey[3] = c.z;  ez[3] = c.w;
            dd[0] = d.x; dd[1] = d.y; dd[2] = d.z; dd[3] = d.w;
            nk = 4;
        } else {
            nk = E - e0;
            for (int k = 0; k < nk; ++k) {
                ex4[k] = bv[3 * (e0 + k) + 0];
                ey[k]  = bv[3 * (e0 + k) + 1];
                ez[k]  = bv[3 * (e0 + k) + 2];
                dd[k]  = dst[e0 + k];
            }
        }
        for (int k = 0; k < nk; ++k) {
            float x = ex4[k], y = ey[k], z = ez[k];
            float r2  = x * x + y * y + z * z;
            float inv = 1.0f / r2;
            float c6  = inv * inv * inv;
            float c12 = c6 * c6;
            esum += 2.0f * (c12 - c6) + HALF_NEG_E0;
            float fs = -24.0f * (2.0f * c12 - c6) * inv * FPSCALE;
            int ix = __float2int_rn(fs * x);
            int iy = __float2int_rn(fs * y);
            int iz = __float2int_rn(fs * z);
            int b  = ((unsigned)dd[k]) >> SHIFT;
            int slot = atomicAdd(&lcur[b], 1);    // native LDS int atomic
            s_ent[slot] = make_int2((ix & 0xffff) | (iy << 16),
                                    (iz & 0xffff) | ((dd[k] & (BK - 1)) << 16));
            s_bkt[slot] = (unsigned char)b;
        }
    }
    __syncthreads();

    // ---- flush: contiguous coalesced write to own region -------------------
    const int nloc = max(0, min(E, ge << 2) - (gs << 2));
    for (int i = t; i < nloc; i += T)
        sorted[(size_t)r * capb + i] = s_ent[i];

    // ---- energy: wave shuffle -> LDS -> one plain store per block ----------
#pragma unroll
    for (int off = 32; off > 0; off >>= 1)
        esum += __shfl_down(esum, off, 64);
    __shared__ float wsum[T / 64];
    const int wid = t >> 6, lid = t & 63;
    if (lid == 0) wsum[wid] = esum;
    __syncthreads();
    if (t == 0) {
        float s = 0.0f;
        for (int w = 0; w < T / 64; ++w) s += wsum[w];
        eblk[r] = s;
    }
}

// ---- Phase 4a: bucket-major partial reduce over a run-subrange -------------
// Grid = NB * Q. Block (b,q) gathers runs r in [q*RPQ, ...) of bucket b with
// QUARTER-WAVE-per-run (16 lanes per run, 4 runs live per wave -> ~81% lane
// efficiency at avg run 26). Accumulate packed u64 XY + int Z in LDS, write
// int partials (deterministic).
__global__ __launch_bounds__(T)
void p4a_partial(const int2* __restrict__ sorted, const int* __restrict__ bmap,
                 unsigned long long* __restrict__ partXY, int* __restrict__ partZ,
                 int NB, int nblk, int capb, int rpq)
{
    __shared__ unsigned long long accXY[BK];      // 8 KB
    __shared__ int accZ[BK];                      // 4 KB
    __shared__ int runsL[RPQ_MAX];                // run directory slice

    const int b = blockIdx.x / Q;
    const int q = blockIdx.x - b * Q;
    const int t = threadIdx.x;

    const int rbeg = q * rpq;
    const int rend = min(nblk, rbeg + rpq);
    const int nr   = rend - rbeg;

    for (int i = t; i < BK; i += T) { accXY[i] = 0ull; accZ[i] = 0; }
    for (int i = t; i < nr; i += T) runsL[i] = bmap[(size_t)(rbeg + i) * NB + b];
    __syncthreads();

    const int wid  = t >> 6;
    const int lane = t & 63;
    const int sub  = lane >> 4;   // quarter-wave id 0..3
    const int l16  = lane & 15;

    // each wave takes 4 runs per iteration (one per quarter-wave)
    for (int rr = 4 * wid; rr < nr; rr += 16) {
        const int ri = rr + sub;
        if (ri < nr) {
            const int m   = runsL[ri];
            const int cnt = m >> 16;
            const int2* src = sorted + (size_t)(rbeg + ri) * capb + (m & 0xffff);
            for (int c = l16; c < cnt; c += 16) {
                int2 v = src[c];
                int lid = ((unsigned)v.y) >> 16;
                unsigned long long p =
                    ((unsigned long long)(unsigned)(v.x >> 16) << 32)
                  + (unsigned long long)(long long)(int)(short)(v.x & 0xffff);
                atomicAdd(&accXY[lid], p);
                atomicAdd(&accZ[lid], (int)(short)(v.y & 0xffff));
            }
        }
    }
    __syncthreads();
    unsigned long long* PX = partXY + (size_t)blockIdx.x * BK;
    int*                PZ = partZ  + (size_t)blockIdx.x * BK;
    for (int i = t; i < BK; i += T) { PX[i] = accXY[i]; PZ[i] = accZ[i]; }
}

// ---- Phase 4b: merge Q packed partials per node, decode, write outputs -----
// Block 0 additionally reduces eblk -> energy (deterministic fixed order).
__global__ __launch_bounds__(T)
void p4b_merge(const unsigned long long* __restrict__ partXY,
               const int* __restrict__ partZ, const float* __restrict__ eblk,
               float* __restrict__ forces, float* __restrict__ analytic,
               float* __restrict__ energy, int N, int nblk)
{
    __shared__ float ws[T / 64];
    const int t = threadIdx.x;

    if (blockIdx.x == 0) {
        float es = 0.0f;
        for (int i = t; i < nblk; i += T) es += eblk[i];
#pragma unroll
        for (int off = 32; off > 0; off >>= 1)
            es += __shfl_down(es, off, 64);
        if ((t & 63) == 0) ws[t >> 6] = es;
        __syncthreads();
        if (t == 0) {
            float s = 0.0f;
            for (int w = 0; w < T / 64; ++w) s += ws[w];
            energy[0] = s;
        }
    }

    const int node = blockIdx.x * T + t;
    if (node >= N) return;
    const int b   = node >> SHIFT;
    const int lid = node & (BK - 1);
    const unsigned long long* PX = partXY + ((size_t)b * Q) * BK + lid;
    const int*                PZ = partZ  + ((size_t)b * Q) * BK + lid;
    unsigned long long sxy = 0ull; int sz = 0;
#pragma unroll
    for (int qq = 0; qq < Q; ++qq) {
        sxy += PX[(size_t)qq * BK];
        sz  += PZ[(size_t)qq * BK];
    }
    int sx = (int)(unsigned)(sxy & 0xffffffffull);
    int sy = (int)(unsigned)(sxy >> 32) + (sx < 0 ? 1 : 0);
    float vx = (float)sx * INV_FPSCALE;
    float vy = (float)sy * INV_FPSCALE;
    float vz = (float)sz * INV_FPSCALE;
    analytic[3 * node + 0] = vx;
    analytic[3 * node + 1] = vy;
    analytic[3 * node + 2] = vz;
    forces[3 * node + 0] = -0.5f * vx;
    forces[3 * node + 1] = -0.5f * vy;
    forces[3 * node + 2] = -0.5f * vz;
}

// ---------------- Fallback if workspace/shape unsupported -------------------
__global__ __launch_bounds__(T)
void lj_fallback(const float* __restrict__ bv, const int* __restrict__ dst,
                 float* __restrict__ out_energy, float* __restrict__ analytic, int E)
{
    const int e = blockIdx.x * blockDim.x + threadIdx.x;
    float esum = 0.0f;
    if (e < E) {
        float x = bv[3 * e], y = bv[3 * e + 1], z = bv[3 * e + 2];
        float r2 = x * x + y * y + z * z;
        float inv = 1.0f / r2;
        float c6 = inv * inv * inv, c12 = c6 * c6;
        esum = 2.0f * (c12 - c6) + HALF_NEG_E0;
        float fs = -24.0f * (2.0f * c12 - c6) * inv;
        float* p = analytic + 3 * (size_t)dst[e];
        unsafeAtomicAdd(p + 0, fs * x);
        unsafeAtomicAdd(p + 1, fs * y);
        unsafeAtomicAdd(p + 2, fs * z);
    }
#pragma unroll
    for (int off = 32; off > 0; off >>= 1) esum += __shfl_down(esum, off, 64);
    __shared__ float wsum[T / 64];
    if ((threadIdx.x & 63) == 0) wsum[threadIdx.x >> 6] = esum;
    __syncthreads();
    if (threadIdx.x == 0) {
        float s = 0.0f;
        for (int w = 0; w < T / 64; ++w) s += wsum[w];
        unsafeAtomicAdd(out_energy, s);
    }
}

__global__ __launch_bounds__(T)
void lj_scale(const float* __restrict__ analytic, float* __restrict__ forces, int n)
{
    int i = blockIdx.x * blockDim.x + threadIdx.x;
    if (i < n) forces[i] = -0.5f * analytic[i];
}

extern "C" void kernel_launch(void* const* d_in, const int* in_sizes, int n_in,
                              void* d_out, int out_size, void* d_ws, size_t ws_size,
                              hipStream_t stream)
{
    const float* bv  = (const float*)d_in[0];
    const int*   dst = (const int*)d_in[1];
    const int E = in_sizes[0] / 3;
    const int N = (out_size - 1) / 6;   // out = [energy | forces(3N) | analytic(3N)]
    if (E <= 0 || N <= 0) return;

    float* out      = (float*)d_out;
    float* energy   = out;
    float* forces   = out + 1;
    float* analytic = out + 1 + (size_t)3 * N;

    const int NB  = (N + BK - 1) / BK;
    const int G   = (E + 3) / 4;
    const int GPB = (G + B1 - 1) / B1;
    const int capb = GPB * 4;
    const int rpq  = (B1 + Q - 1) / Q;

    auto al = [](size_t x) { return (x + 255) & ~(size_t)255; };
    const size_t sorted_bytes = al((size_t)B1 * capb * 8);
    const size_t bmap_bytes   = al((size_t)B1 * NB * 4);
    const size_t eblk_bytes   = al((size_t)B1 * 4);
    const size_t partXY_bytes = al((size_t)NB * Q * BK * 8);
    const size_t partZ_bytes  = al((size_t)NB * Q * BK * 4);
    const size_t need = sorted_bytes + bmap_bytes + eblk_bytes
                      + partXY_bytes + partZ_bytes;

    // p3 smem ints: s_ent(2*capb) + s_bkt(ceil(capb/4)) + lcur(NB)
    const size_t smem_bytes = (size_t)capb * 8 + ((size_t)(capb + 3) / 4) * 4
                            + (size_t)NB * 4;

    if (NB <= 128 && capb >= 128 && capb < 32768 && rpq <= RPQ_MAX
        && smem_bytes <= 64000 && ws_size >= need) {
        char* w = (char*)d_ws;
        int2*               sorted = (int2*)w;               w += sorted_bytes;
        int*                bmap   = (int*)w;                w += bmap_bytes;
        float*              eblk   = (float*)w;              w += eblk_bytes;
        unsigned long long* partXY = (unsigned long long*)w; w += partXY_bytes;
        int*                partZ  = (int*)w;

        p3_fused   <<<B1, T, smem_bytes, stream>>>(bv, dst, bmap, sorted, eblk,
                                                   E, NB, GPB, capb);
        p4a_partial<<<NB * Q, T, 0, stream>>>(sorted, bmap, partXY, partZ,
                                              NB, B1, capb, rpq);
        p4b_merge  <<<(N + T - 1) / T, T, 0, stream>>>(partXY, partZ, eblk,
                                                       forces, analytic, energy,
                                                       N, B1);
    } else {
        hipMemsetAsync(d_out, 0, (size_t)out_size * sizeof(float), stream);
        lj_fallback<<<(E + T - 1) / T, T, 0, stream>>>(bv, dst, energy, analytic, E);
        const int n3 = 3 * N;
        lj_scale<<<(n3 + T - 1) / T, T, 0, stream>>>(analytic, forces, n3);
    }
}

// Round 11
// 167.614 us; speedup vs baseline: 2.8284x; 1.0220x over previous
//
#include <hip/hip_runtime.h>
#include <math.h>

// e0 = 4*((1/3)^12 - (1/3)^6); 0.5*pe = 2*(c12 - c6) - 0.5*e0
static constexpr float HALF_NEG_E0 = 2.739720872e-3f; // -0.5*e0

#define T 256           // threads per block
#define B1 2500         // blocks for p3
#define SHIFT 10
#define BK 1024         // nodes per bucket (lid fits in 10 bits)
#define Q 8             // gather sub-blocks per bucket in p4a
#define RPQ_MAX 352     // max runs per p4a block (ceil(B1/Q)=313)
#define FPSCALE 512.0f  // |f| <= 59.5 -> |int| <= 30450 < 32767
#define INV_FPSCALE (1.0f / 512.0f)

// ---- Phase 3: deterministic staging (NO global atomics, NO memsets).
//      R11: dst cached in registers across both passes (single global read),
//      all bv float4 loads issued before the scan (latency hides under it),
//      scan via two 64-lane shuffle scans (2 barriers instead of 14).
__global__ __launch_bounds__(T)
void p3_fused(const float* __restrict__ bv, const int* __restrict__ dst,
              int* __restrict__ bmap, int2* __restrict__ sorted,
              float* __restrict__ eblk, int E, int NB, int GPB, int capb)
{
    extern __shared__ int smem[];
    int2*          s_ent = (int2*)smem;                       // [capb]
    unsigned char* s_bkt = (unsigned char*)(smem + 2 * capb); // [capb]
    int* lcur = smem + 2 * capb + (capb + 3) / 4;             // [NB]
    __shared__ int   wtot[2];
    __shared__ float wsum[T / 64];

    const int r = blockIdx.x;
    const int t = threadIdx.x;

    const int G  = (E + 3) >> 2;
    const int gs = r * GPB;
    const int ge = min(G, gs + GPB);
    const int4*   __restrict__ d4  = (const int4*)dst;
    const float4* __restrict__ bv4 = (const float4*)bv;

    // up to 3 groups per thread (launcher guards GPB <= 3*T)
    const int g0 = gs + t, g1 = g0 + T, g2 = g1 + T;
    const bool v0 = g0 < ge, v1 = g1 < ge, v2 = g2 < ge;
    const bool f0 = v0 && ((g0 << 2) + 3 < E);
    const bool f1 = v1 && ((g1 << 2) + 3 < E);
    const bool f2 = v2 && ((g2 << 2) + 3 < E);

    // ---- issue ALL global loads up front: dst, then bv ---------------------
    int4 dA, dB, dC;
    if (f0) dA = d4[g0];
    if (f1) dB = d4[g1];
    if (f2) dC = d4[g2];
    float4 aA, bA, cA, aB, bB, cB, aC, bC, cC;
    if (f0) { aA = bv4[3 * g0]; bA = bv4[3 * g0 + 1]; cA = bv4[3 * g0 + 2]; }
    if (f1) { aB = bv4[3 * g1]; bB = bv4[3 * g1 + 1]; cB = bv4[3 * g1 + 2]; }
    if (f2) { aC = bv4[3 * g2]; bC = bv4[3 * g2 + 1]; cC = bv4[3 * g2 + 2]; }

    for (int b = t; b < NB; b += T) lcur[b] = 0;
    __syncthreads();

    // ---- pass A: histogram from registers (native LDS int atomics) ---------
    if (f0) {
        atomicAdd(&lcur[((unsigned)dA.x) >> SHIFT], 1);
        atomicAdd(&lcur[((unsigned)dA.y) >> SHIFT], 1);
        atomicAdd(&lcur[((unsigned)dA.z) >> SHIFT], 1);
        atomicAdd(&lcur[((unsigned)dA.w) >> SHIFT], 1);
    } else if (v0) {
        for (int e = g0 << 2; e < E; ++e)
            atomicAdd(&lcur[((unsigned)dst[e]) >> SHIFT], 1);
    }
    if (f1) {
        atomicAdd(&lcur[((unsigned)dB.x) >> SHIFT], 1);
        atomicAdd(&lcur[((unsigned)dB.y) >> SHIFT], 1);
        atomicAdd(&lcur[((unsigned)dB.z) >> SHIFT], 1);
        atomicAdd(&lcur[((unsigned)dB.w) >> SHIFT], 1);
    } else if (v1) {
        for (int e = g1 << 2; e < E; ++e)
            atomicAdd(&lcur[((unsigned)dst[e]) >> SHIFT], 1);
    }
    if (f2) {
        atomicAdd(&lcur[((unsigned)dC.x) >> SHIFT], 1);
        atomicAdd(&lcur[((unsigned)dC.y) >> SHIFT], 1);
        atomicAdd(&lcur[((unsigned)dC.z) >> SHIFT], 1);
        atomicAdd(&lcur[((unsigned)dC.w) >> SHIFT], 1);
    } else if (v2) {
        for (int e = g2 << 2; e < E; ++e)
            atomicAdd(&lcur[((unsigned)dst[e]) >> SHIFT], 1);
    }
    __syncthreads();

    // ---- exclusive scan of lcur[0..NB) via two 64-lane shuffle scans -------
    {
        const int lane = t & 63, wid = t >> 6;
        int v = (t < 128 && t < NB) ? lcur[t] : 0;
        if (t < 128) {
#pragma unroll
            for (int off = 1; off < 64; off <<= 1) {
                int u = __shfl_up(v, off, 64);
                if (lane >= off) v += u;
            }
            if (lane == 63) wtot[wid] = v;
        }
        __syncthreads();
        if (t < NB) {
            int incl = v + ((t >= 64) ? wtot[0] : 0);
            int cnt  = lcur[t];
            int ex   = incl - cnt;                // exclusive prefix
            bmap[(size_t)r * NB + t] = ex | (cnt << 16);
            lcur[t] = ex;                         // becomes slot cursor
        }
    }
    __syncthreads();

    // ---- pass B: compute forces + energy from prefetched registers ---------
    float esum = 0.0f;

    auto edge1 = [&](float x, float y, float z, int node) {
        float r2  = x * x + y * y + z * z;
        float inv = 1.0f / r2;
        float c6  = inv * inv * inv;
        float c12 = c6 * c6;
        esum += 2.0f * (c12 - c6) + HALF_NEG_E0;
        float fs = -24.0f * (2.0f * c12 - c6) * inv * FPSCALE;
        int ix = __float2int_rn(fs * x);
        int iy = __float2int_rn(fs * y);
        int iz = __float2int_rn(fs * z);
        int b  = ((unsigned)node) >> SHIFT;
        int slot = atomicAdd(&lcur[b], 1);        // native LDS int atomic
        s_ent[slot] = make_int2((ix & 0xffff) | (iy << 16),
                                (iz & 0xffff) | ((node & (BK - 1)) << 16));
        s_bkt[slot] = (unsigned char)b;
    };

    if (f0) {
        edge1(aA.x, aA.y, aA.z, dA.x);
        edge1(aA.w, bA.x, bA.y, dA.y);
        edge1(bA.z, bA.w, cA.x, dA.z);
        edge1(cA.y, cA.z, cA.w, dA.w);
    } else if (v0) {
        for (int e = g0 << 2; e < E; ++e)
            edge1(bv[3 * e], bv[3 * e + 1], bv[3 * e + 2], dst[e]);
    }
    if (f1) {
        edge1(aB.x, aB.y, aB.z, dB.x);
        edge1(aB.w, bB.x, bB.y, dB.y);
        edge1(bB.z, bB.w, cB.x, dB.z);
        edge1(cB.y, cB.z, cB.w, dB.w);
    } else if (v1) {
        for (int e = g1 << 2; e < E; ++e)
            edge1(bv[3 * e], bv[3 * e + 1], bv[3 * e + 2], dst[e]);
    }
    if (f2) {
        edge1(aC.x, aC.y, aC.z, dC.x);
        edge1(aC.w, bC.x, bC.y, dC.y);
        edge1(bC.z, bC.w, cC.x, dC.z);
        edge1(cC.y, cC.z, cC.w, dC.w);
    } else if (v2) {
        for (int e = g2 << 2; e < E; ++e)
            edge1(bv[3 * e], bv[3 * e + 1], bv[3 * e + 2], dst[e]);
    }
    __syncthreads();

    // ---- flush: contiguous coalesced write to own region -------------------
    const int nloc = max(0, min(E, ge << 2) - (gs << 2));
    for (int i = t; i < nloc; i += T)
        sorted[(size_t)r * capb + i] = s_ent[i];

    // ---- energy: wave shuffle -> LDS -> one plain store per block ----------
#pragma unroll
    for (int off = 32; off > 0; off >>= 1)
        esum += __shfl_down(esum, off, 64);
    const int wid = t >> 6, lid = t & 63;
    if (lid == 0) wsum[wid] = esum;
    __syncthreads();
    if (t == 0) {
        float s = 0.0f;
        for (int w = 0; w < T / 64; ++w) s += wsum[w];
        eblk[r] = s;
    }
}

// ---- Phase 4a: bucket-major partial reduce over a run-subrange -------------
// (unchanged from R10, verified) Quarter-wave-per-run gather, packed u64 LDS
// accumulate, deterministic int partials.
__global__ __launch_bounds__(T)
void p4a_partial(const int2* __restrict__ sorted, const int* __restrict__ bmap,
                 unsigned long long* __restrict__ partXY, int* __restrict__ partZ,
                 int NB, int nblk, int capb, int rpq)
{
    __shared__ unsigned long long accXY[BK];      // 8 KB
    __shared__ int accZ[BK];                      // 4 KB
    __shared__ int runsL[RPQ_MAX];                // run directory slice

    const int b = blockIdx.x / Q;
    const int q = blockIdx.x - b * Q;
    const int t = threadIdx.x;

    const int rbeg = q * rpq;
    const int rend = min(nblk, rbeg + rpq);
    const int nr   = rend - rbeg;

    for (int i = t; i < BK; i += T) { accXY[i] = 0ull; accZ[i] = 0; }
    for (int i = t; i < nr; i += T) runsL[i] = bmap[(size_t)(rbeg + i) * NB + b];
    __syncthreads();

    const int wid  = t >> 6;
    const int lane = t & 63;
    const int sub  = lane >> 4;   // quarter-wave id 0..3
    const int l16  = lane & 15;

    for (int rr = 4 * wid; rr < nr; rr += 16) {
        const int ri = rr + sub;
        if (ri < nr) {
            const int m   = runsL[ri];
            const int cnt = m >> 16;
            const int2* src = sorted + (size_t)(rbeg + ri) * capb + (m & 0xffff);
            for (int c = l16; c < cnt; c += 16) {
                int2 v = src[c];
                int lid = ((unsigned)v.y) >> 16;
                unsigned long long p =
                    ((unsigned long long)(unsigned)(v.x >> 16) << 32)
                  + (unsigned long long)(long long)(int)(short)(v.x & 0xffff);
                atomicAdd(&accXY[lid], p);
                atomicAdd(&accZ[lid], (int)(short)(v.y & 0xffff));
            }
        }
    }
    __syncthreads();
    unsigned long long* PX = partXY + (size_t)blockIdx.x * BK;
    int*                PZ = partZ  + (size_t)blockIdx.x * BK;
    for (int i = t; i < BK; i += T) { PX[i] = accXY[i]; PZ[i] = accZ[i]; }
}

// ---- Phase 4b: merge Q packed partials per node, decode, write outputs -----
// (unchanged from R10, verified)
__global__ __launch_bounds__(T)
void p4b_merge(const unsigned long long* __restrict__ partXY,
               const int* __restrict__ partZ, const float* __restrict__ eblk,
               float* __restrict__ forces, float* __restrict__ analytic,
               float* __restrict__ energy, int N, int nblk)
{
    __shared__ float ws[T / 64];
    const int t = threadIdx.x;

    if (blockIdx.x == 0) {
        float es = 0.0f;
        for (int i = t; i < nblk; i += T) es += eblk[i];
#pragma unroll
        for (int off = 32; off > 0; off >>= 1)
            es += __shfl_down(es, off, 64);
        if ((t & 63) == 0) ws[t >> 6] = es;
        __syncthreads();
        if (t == 0) {
            float s = 0.0f;
            for (int w = 0; w < T / 64; ++w) s += ws[w];
            energy[0] = s;
        }
    }

    const int node = blockIdx.x * T + t;
    if (node >= N) return;
    const int b   = node >> SHIFT;
    const int lid = node & (BK - 1);
    const unsigned long long* PX = partXY + ((size_t)b * Q) * BK + lid;
    const int*                PZ = partZ  + ((size_t)b * Q) * BK + lid;
    unsigned long long sxy = 0ull; int sz = 0;
#pragma unroll
    for (int qq = 0; qq < Q; ++qq) {
        sxy += PX[(size_t)qq * BK];
        sz  += PZ[(size_t)qq * BK];
    }
    int sx = (int)(unsigned)(sxy & 0xffffffffull);
    int sy = (int)(unsigned)(sxy >> 32) + (sx < 0 ? 1 : 0);
    float vx = (float)sx * INV_FPSCALE;
    float vy = (float)sy * INV_FPSCALE;
    float vz = (float)sz * INV_FPSCALE;
    analytic[3 * node + 0] = vx;
    analytic[3 * node + 1] = vy;
    analytic[3 * node + 2] = vz;
    forces[3 * node + 0] = -0.5f * vx;
    forces[3 * node + 1] = -0.5f * vy;
    forces[3 * node + 2] = -0.5f * vz;
}

// ---------------- Fallback if workspace/shape unsupported -------------------
__global__ __launch_bounds__(T)
void lj_fallback(const float* __restrict__ bv, const int* __restrict__ dst,
                 float* __restrict__ out_energy, float* __restrict__ analytic, int E)
{
    const int e = blockIdx.x * blockDim.x + threadIdx.x;
    float esum = 0.0f;
    if (e < E) {
        float x = bv[3 * e], y = bv[3 * e + 1], z = bv[3 * e + 2];
        float r2 = x * x + y * y + z * z;
        float inv = 1.0f / r2;
        float c6 = inv * inv * inv, c12 = c6 * c6;
        esum = 2.0f * (c12 - c6) + HALF_NEG_E0;
        float fs = -24.0f * (2.0f * c12 - c6) * inv;
        float* p = analytic + 3 * (size_t)dst[e];
        unsafeAtomicAdd(p + 0, fs * x);
        unsafeAtomicAdd(p + 1, fs * y);
        unsafeAtomicAdd(p + 2, fs * z);
    }
#pragma unroll
    for (int off = 32; off > 0; off >>= 1) esum += __shfl_down(esum, off, 64);
    __shared__ float wsum[T / 64];
    if ((threadIdx.x & 63) == 0) wsum[threadIdx.x >> 6] = esum;
    __syncthreads();
    if (threadIdx.x == 0) {
        float s = 0.0f;
        for (int w = 0; w < T / 64; ++w) s += wsum[w];
        unsafeAtomicAdd(out_energy, s);
    }
}

__global__ __launch_bounds__(T)
void lj_scale(const float* __restrict__ analytic, float* __restrict__ forces, int n)
{
    int i = blockIdx.x * blockDim.x + threadIdx.x;
    if (i < n) forces[i] = -0.5f * analytic[i];
}

extern "C" void kernel_launch(void* const* d_in, const int* in_sizes, int n_in,
                              void* d_out, int out_size, void* d_ws, size_t ws_size,
                              hipStream_t stream)
{
    const float* bv  = (const float*)d_in[0];
    const int*   dst = (const int*)d_in[1];
    const int E = in_sizes[0] / 3;
    const int N = (out_size - 1) / 6;   // out = [energy | forces(3N) | analytic(3N)]
    if (E <= 0 || N <= 0) return;

    float* out      = (float*)d_out;
    float* energy   = out;
    float* forces   = out + 1;
    float* analytic = out + 1 + (size_t)3 * N;

    const int NB  = (N + BK - 1) / BK;
    const int G   = (E + 3) / 4;
    const int GPB = (G + B1 - 1) / B1;
    const int capb = GPB * 4;
    const int rpq  = (B1 + Q - 1) / Q;

    auto al = [](size_t x) { return (x + 255) & ~(size_t)255; };
    const size_t sorted_bytes = al((size_t)B1 * capb * 8);
    const size_t bmap_bytes   = al((size_t)B1 * NB * 4);
    const size_t eblk_bytes   = al((size_t)B1 * 4);
    const size_t partXY_bytes = al((size_t)NB * Q * BK * 8);
    const size_t partZ_bytes  = al((size_t)NB * Q * BK * 4);
    const size_t need = sorted_bytes + bmap_bytes + eblk_bytes
                      + partXY_bytes + partZ_bytes;

    // p3 smem ints: s_ent(2*capb) + s_bkt(ceil(capb/4)) + lcur(NB)
    const size_t smem_bytes = (size_t)capb * 8 + ((size_t)(capb + 3) / 4) * 4
                            + (size_t)NB * 4;

    if (NB <= 128 && capb >= 128 && capb < 32768 && GPB <= 3 * T
        && rpq <= RPQ_MAX && smem_bytes <= 64000 && ws_size >= need) {
        char* w = (char*)d_ws;
        int2*               sorted = (int2*)w;               w += sorted_bytes;
        int*                bmap   = (int*)w;                w += bmap_bytes;
        float*              eblk   = (float*)w;              w += eblk_bytes;
        unsigned long long* partXY = (unsigned long long*)w; w += partXY_bytes;
        int*                partZ  = (int*)w;

        p3_fused   <<<B1, T, smem_bytes, stream>>>(bv, dst, bmap, sorted, eblk,
                                                   E, NB, GPB, capb);
        p4a_partial<<<NB * Q, T, 0, stream>>>(sorted, bmap, partXY, partZ,
                                              NB, B1, capb, rpq);
        p4b_merge  <<<(N + T - 1) / T, T, 0, stream>>>(partXY, partZ, eblk,
                                                       forces, analytic, energy,
                                                       N, B1);
    } else {
        hipMemsetAsync(d_out, 0, (size_t)out_size * sizeof(float), stream);
        lj_fallback<<<(E + T - 1) / T, T, 0, stream>>>(bv, dst, energy, analytic, E);
        const int n3 = 3 * N;
        lj_scale<<<(n3 + T - 1) / T, T, 0, stream>>>(analytic, forces, n3);
    }
}